// Round 13
// baseline (207.943 us; speedup 1.0000x reference)
//
#include <hip/hip_runtime.h>
#include <math.h>

// Problem constants (from reference setup_inputs)
#define NB     64      // batch
#define N1V    8192    // obj points per batch
#define NPTS   (NB * N1V)
#define NV     778     // recon / gt verts
#define NVP    780     // padded to multiple of 4
#define NQ     195     // target quads
#define SEG1Q  51      // first 51 quads = 204 permuted targets = PRIOR set
#define NFACE  1538
#define NZ     64
#define NPAR   61
#define NPRIOR 204
#define PPT    8       // obj points per thread (rec/gt roles)
#define BIAS   0.0625f // 2|a||t| <= 0.06 < BIAS -> biased rec partials stay >= 0

// roles
#define REC_BLOCKS 256                 // (batch, chunk-of-2048)
#define GT_BLOCKS  256
#define CH_BLOCKS  128                 // (batch, dir)
#define NROLE (REC_BLOCKS + GT_BLOCKS + CH_BLOCKS)   // 640

// ws float offsets (no prep arrays anymore)
#define PART_OFF 0                     // float[NROLE][4], every row fully written
#define RC_OFF   (NROLE * 4)           // 16384 uints = rec-cmap bits (1/pt)
#define GC_OFF   (RC_OFF + 16384)      // 16384 uints = gt-cmap bits

__device__ __constant__ int c_prior[NPRIOR] = {
  697,698,699,700,712,713,714,715,737,738,739,740,741,743,744,745,746,748,749,750,
  753,754,755,756,757,758,759,760,761,762,763,764,765,766,767,768,
  46,47,48,49,164,165,166,167,194,195,223,237,238,280,281,298,301,317,320,323,
  324,325,326,327,328,329,330,331,332,333,340,341,342,343,344,345,346,347,348,349,
  350,351,352,353,354,355,
  356,357,358,359,375,376,386,387,396,397,402,403,413,429,433,434,435,436,437,438,
  439,440,441,442,443,444,452,453,454,455,456,459,460,461,462,463,464,465,466,467,
  468,469,470,471,484,485,486,496,497,506,507,513,514,524,545,546,547,548,549,550,
  551,552,553,555,563,564,565,566,567,570,572,573,574,575,576,577,578,
  580,581,582,583,600,601,602,614,615,624,625,630,631,641,663,664,665,666,667,668,
  670,672,680,681,682,683,684,686,687,688,689,690,691,692,693,694,695,
  73,96,98,99,772,774,775,777
};

#define LOAD_PTS(ob)                                                          \
    const float4* ob4 = (const float4*)((ob) + (size_t)tid * 24);             \
    float4 q0 = ob4[0], q1 = ob4[1], q2 = ob4[2],                             \
           q3 = ob4[3], q4 = ob4[4], q5 = ob4[5];                             \
    float px[PPT], py[PPT], pz[PPT];                                          \
    px[0]=q0.x; py[0]=q0.y; pz[0]=q0.z;  px[1]=q0.w; py[1]=q1.x; pz[1]=q1.y;  \
    px[2]=q1.z; py[2]=q1.w; pz[2]=q2.x;  px[3]=q2.y; py[3]=q2.z; pz[3]=q2.w;  \
    px[4]=q3.x; py[4]=q3.y; pz[4]=q3.z;  px[5]=q3.w; py[5]=q4.x; pz[5]=q4.y;  \
    px[6]=q4.z; py[6]=q4.w; pz[6]=q5.x;  px[7]=q5.y; py[7]=q5.z; pz[7]=q5.w;

// ---------------- One fused kernel: all roles, self-sufficient ----------------
// [0,256): rec (in-block perm + normals + scan + epilogue)
// [256,512): gt (direct stage + scan + gc bits)   [512,640): chamfer
__global__ __launch_bounds__(256) void k_all(const float* __restrict__ obj,
                                             const float* __restrict__ recon,
                                             const float* __restrict__ gt,
                                             const int* __restrict__ faces,
                                             float* __restrict__ part,
                                             unsigned char* __restrict__ rcA,
                                             unsigned char* __restrict__ gcA) {
    __shared__ float4 s_t[NVP];
    __shared__ float s_vnx[NV], s_vny[NV], s_vnz[NV];
    __shared__ unsigned short s_perm[NV];
    __shared__ unsigned int s_bm[25];
    __shared__ unsigned short s_pre[26];
    __shared__ float s_red[4];
    int tid = threadIdx.x;
    int blk = blockIdx.x;

    if (blk < REC_BLOCKS) {
        // ============ REC ROLE: in-block prep + scan + inline epilogue ========
        int b = blk >> 2, chunk = blk & 3;
        const float* rb = recon + (size_t)b * NV * 3;

        if (tid < 25) s_bm[tid] = 0u;
        if (tid < 4) s_red[tid] = 0.0f;
        for (int j = tid; j < NV; j += 256) {
            s_vnx[j] = 0.0f; s_vny[j] = 0.0f; s_vnz[j] = 0.0f;
        }
        __syncthreads();
        if (tid < NPRIOR) {
            int v = c_prior[tid];
            atomicOr(&s_bm[v >> 5], 1u << (v & 31));
        }
        __syncthreads();
        if (tid == 0) {
            unsigned int run = 0;
            for (int w = 0; w < 25; ++w) { s_pre[w] = (unsigned short)run; run += __popc(s_bm[w]); }
            s_pre[25] = (unsigned short)run;
        }
        __syncthreads();
        for (int j = tid; j < NV; j += 256) {
            int w = j >> 5;
            unsigned int below = s_bm[w] & ((1u << (j & 31)) - 1u);
            int rank = s_pre[w] + __popc(below);
            bool member = (s_bm[w] >> (j & 31)) & 1u;
            int pos = member ? rank : (NPRIOR + (j - rank));
            s_perm[pos] = (unsigned short)j;
        }
        __syncthreads();
        // stage permuted targets (prior first) with biased w
        for (int j = tid; j < NVP; j += 256) {
            if (j < NV) {
                int src = s_perm[j];
                float x = rb[3*src], y = rb[3*src+1], z = rb[3*src+2];
                s_t[j] = make_float4(x, y, z, x*x + y*y + z*z + BIAS);
            } else {
                s_t[j] = make_float4(0.f, 0.f, 0.f, 1e30f);
            }
        }
        // face normals (redundant per rec block; reads recon from global/L1)
        for (int f = tid; f < NFACE; f += 256) {
            int i0 = faces[3*f], i1 = faces[3*f+1], i2 = faces[3*f+2];
            float p0x = rb[3*i0], p0y = rb[3*i0+1], p0z = rb[3*i0+2];
            float e1x = rb[3*i1]   - p0x, e1y = rb[3*i1+1] - p0y, e1z = rb[3*i1+2] - p0z;
            float e2x = rb[3*i2]   - p0x, e2y = rb[3*i2+1] - p0y, e2z = rb[3*i2+2] - p0z;
            float fx = e1y * e2z - e1z * e2y;
            float fy = e1z * e2x - e1x * e2z;
            float fz = e1x * e2y - e1y * e2x;
            atomicAdd(&s_vnx[i0], fx); atomicAdd(&s_vny[i0], fy); atomicAdd(&s_vnz[i0], fz);
            atomicAdd(&s_vnx[i1], fx); atomicAdd(&s_vny[i1], fy); atomicAdd(&s_vnz[i1], fz);
            atomicAdd(&s_vnx[i2], fx); atomicAdd(&s_vny[i2], fy); atomicAdd(&s_vnz[i2], fz);
        }
        __syncthreads();
        for (int j = tid; j < NV; j += 256) {
            float x = s_vnx[j], y = s_vny[j], z = s_vnz[j];
            float inv = 1.0f / (sqrtf(x*x + y*y + z*z) + 1e-12f);
            s_vnx[j] = x * inv; s_vny[j] = y * inv; s_vnz[j] = z * inv;
        }
        __syncthreads();

        const float* ob = obj + ((size_t)b * N1V + (size_t)chunk * 2048) * 3;
        LOAD_PTS(ob)
        float nax[PPT], nay[PPT], naz[PPT], m[PPT];
        int q[PPT];
#pragma unroll
        for (int i = 0; i < PPT; ++i) {
            nax[i] = -2.0f * px[i]; nay[i] = -2.0f * py[i]; naz[i] = -2.0f * pz[i];
            m[i] = 3.4e38f; q[i] = 0;
        }
        float mp[PPT];
#pragma unroll 1
        for (int jq = 0; jq < SEG1Q; ++jq) {
            int j = 4 * jq;
            float4 t0 = s_t[j], t1 = s_t[j+1], t2 = s_t[j+2], t3 = s_t[j+3];
#pragma unroll
            for (int i = 0; i < PPT; ++i) {
                float d0 = fmaf(nax[i], t0.x, fmaf(nay[i], t0.y, fmaf(naz[i], t0.z, t0.w)));
                float d1 = fmaf(nax[i], t1.x, fmaf(nay[i], t1.y, fmaf(naz[i], t1.z, t1.w)));
                float d2 = fmaf(nax[i], t2.x, fmaf(nay[i], t2.y, fmaf(naz[i], t2.z, t2.w)));
                float d3 = fmaf(nax[i], t3.x, fmaf(nay[i], t3.y, fmaf(naz[i], t3.z, t3.w)));
                float mn = fminf(fminf(fminf(d0, d1), fminf(d2, d3)), m[i]);
                q[i] = (mn < m[i]) ? jq : q[i];
                m[i] = mn;
            }
        }
#pragma unroll
        for (int i = 0; i < PPT; ++i) mp[i] = m[i];   // prior min snapshot
#pragma unroll 1
        for (int jq = SEG1Q; jq < NQ; ++jq) {
            int j = 4 * jq;
            float4 t0 = s_t[j], t1 = s_t[j+1], t2 = s_t[j+2], t3 = s_t[j+3];
#pragma unroll
            for (int i = 0; i < PPT; ++i) {
                float d0 = fmaf(nax[i], t0.x, fmaf(nay[i], t0.y, fmaf(naz[i], t0.z, t0.w)));
                float d1 = fmaf(nax[i], t1.x, fmaf(nay[i], t1.y, fmaf(naz[i], t1.z, t1.w)));
                float d2 = fmaf(nax[i], t2.x, fmaf(nay[i], t2.y, fmaf(naz[i], t2.z, t2.w)));
                float d3 = fmaf(nax[i], t3.x, fmaf(nay[i], t3.y, fmaf(naz[i], t3.z, t3.w)));
                float mn = fminf(fminf(fminf(d0, d1), fminf(d2, d3)), m[i]);
                q[i] = (mn < m[i]) ? jq : q[i];
                m[i] = mn;
            }
        }
        // ---- inline epilogue ----
        float lS_cmap = 0.0f, lN_cmap = 0.0f, lS_pen = 0.0f;
        unsigned int rcbits = 0;
#pragma unroll
        for (int i = 0; i < PPT; ++i) {
            float a2 = px[i]*px[i] + py[i]*py[i] + pz[i]*pz[i];
            float drec = fmaxf(a2 + (m[i]  - BIAS), 0.0f);
            float dpri = fmaxf(a2 + (mp[i] - BIAS), 0.0f);
            bool cm = drec < 1e-4f;
            bool rc = sqrtf(drec) < 0.005f;
            if (cm) { lS_cmap += dpri; lN_cmap += 1.0f; }
            if (rc) rcbits |= (1u << i);
            // winning-quad re-eval from LDS for jstar (bit-identical fma chain)
            int jr = 4 * q[i];
            float4 t0 = s_t[jr], t1 = s_t[jr+1], t2 = s_t[jr+2], t3 = s_t[jr+3];
            float d0 = fmaf(nax[i], t0.x, fmaf(nay[i], t0.y, fmaf(naz[i], t0.z, t0.w)));
            float d1 = fmaf(nax[i], t1.x, fmaf(nay[i], t1.y, fmaf(naz[i], t1.z, t1.w)));
            float d2 = fmaf(nax[i], t2.x, fmaf(nay[i], t2.y, fmaf(naz[i], t2.z, t2.w)));
            float d3 = fmaf(nax[i], t3.x, fmaf(nay[i], t3.y, fmaf(naz[i], t3.z, t3.w)));
            float mmin = fminf(fminf(d0, d1), fminf(d2, d3));
            int off = (d0 == mmin) ? 0 : ((d1 == mmin) ? 1 : ((d2 == mmin) ? 2 : 3));
            int jstar = jr + off;
            float4 tS = s_t[jstar];
            int jo = s_perm[jstar];
            float ddot = (tS.x - px[i]) * s_vnx[jo] + (tS.y - py[i]) * s_vny[jo]
                       + (tS.z - pz[i]) * s_vnz[jo];
            if (ddot > 0.0f) lS_pen += drec;
        }
        rcA[(size_t)blk * 256 + tid] = (unsigned char)rcbits;
        atomicAdd(&s_red[0], lS_cmap);
        atomicAdd(&s_red[1], lN_cmap);
        atomicAdd(&s_red[2], lS_pen);
        __syncthreads();
        if (tid < 4) {
            float v = (tid < 3) ? s_red[tid] : 0.0f;   // S_cmap, N_cmap, S_pen, 0
            part[(size_t)blk * 4 + tid] = v;
        }
        return;
    }

    if (blk < REC_BLOCKS + GT_BLOCKS) {
        // ============ GT ROLE: direct stage + min scan + gc bits ============
        int r = blk - REC_BLOCKS;
        int b = r >> 2, chunk = r & 3;
        const float* gb = gt + (size_t)b * NV * 3;
        for (int j = tid; j < NVP; j += 256) {
            if (j < NV) {
                float x = gb[3*j], y = gb[3*j+1], z = gb[3*j+2];
                s_t[j] = make_float4(x, y, z, x*x + y*y + z*z);
            } else {
                s_t[j] = make_float4(0.f, 0.f, 0.f, 1e30f);
            }
        }
        if (tid == 0) s_red[0] = 0.0f;
        __syncthreads();

        const float* ob = obj + ((size_t)b * N1V + (size_t)chunk * 2048) * 3;
        LOAD_PTS(ob)
        float nax[PPT], nay[PPT], naz[PPT], mgt[PPT];
#pragma unroll
        for (int i = 0; i < PPT; ++i) {
            nax[i] = -2.0f * px[i]; nay[i] = -2.0f * py[i]; naz[i] = -2.0f * pz[i];
            mgt[i] = 3.4e38f;
        }
#pragma unroll 1
        for (int jq = 0; jq < NQ; ++jq) {
            int j = 4 * jq;
            float4 t0 = s_t[j], t1 = s_t[j+1], t2 = s_t[j+2], t3 = s_t[j+3];
#pragma unroll
            for (int i = 0; i < PPT; ++i) {
                float d0 = fmaf(nax[i], t0.x, fmaf(nay[i], t0.y, fmaf(naz[i], t0.z, t0.w)));
                float d1 = fmaf(nax[i], t1.x, fmaf(nay[i], t1.y, fmaf(naz[i], t1.z, t1.w)));
                float d2 = fmaf(nax[i], t2.x, fmaf(nay[i], t2.y, fmaf(naz[i], t2.z, t2.w)));
                float d3 = fmaf(nax[i], t3.x, fmaf(nay[i], t3.y, fmaf(naz[i], t3.z, t3.w)));
                mgt[i] = fminf(fminf(mgt[i], fminf(d0, d1)), fminf(d2, d3));
            }
        }
        float lN_gt = 0.0f;
        unsigned int gcbits = 0;
#pragma unroll
        for (int i = 0; i < PPT; ++i) {
            float a2 = px[i]*px[i] + py[i]*py[i] + pz[i]*pz[i];
            float dgt = fmaxf(a2 + mgt[i], 0.0f);
            if (sqrtf(dgt) < 0.005f) { lN_gt += 1.0f; gcbits |= (1u << i); }
        }
        gcA[(size_t)r * 256 + tid] = (unsigned char)gcbits;
        atomicAdd(&s_red[0], lN_gt);
        __syncthreads();
        if (tid < 4) part[(size_t)blk * 4 + tid] = (tid == 0) ? s_red[0] : 0.0f;
        return;
    }

    // ============ CHAMFER ROLE (4 sources/thread, direct stage) ============
    {
        int c   = blk - (REC_BLOCKS + GT_BLOCKS);
        int b   = c >> 1;
        int dir = c & 1;           // 0: rec->gt, 1: gt->rec
        const float* sbase = (dir ? gt : recon) + (size_t)b * NV * 3;
        const float* tbase = (dir ? recon : gt) + (size_t)b * NV * 3;
        float tb_bias = dir ? BIAS : 0.0f;   // rec set carries +BIAS
        float sb_bias = dir ? 0.0f : BIAS;
        for (int j = tid; j < NVP; j += 256) {
            if (j < NV) {
                float x = tbase[3*j], y = tbase[3*j+1], z = tbase[3*j+2];
                s_t[j] = make_float4(x, y, z, x*x + y*y + z*z + tb_bias);
            } else {
                s_t[j] = make_float4(0.f, 0.f, 0.f, 1e30f);
            }
        }
        if (tid == 0) s_red[0] = 0.0f;
        __syncthreads();

        const int CPT = 4;
        float nax[CPT], nay[CPT], naz[CPT], a2[CPT], m[CPT];
        bool valid[CPT];
#pragma unroll
        for (int k = 0; k < CPT; ++k) {
            int p = tid + 256 * k;
            valid[k] = (p < NV);
            int pp = valid[k] ? p : 0;
            float x = sbase[3*pp], y = sbase[3*pp+1], z = sbase[3*pp+2];
            nax[k] = -2.0f * x; nay[k] = -2.0f * y; naz[k] = -2.0f * z;
            a2[k] = x*x + y*y + z*z + sb_bias;
            m[k] = 3.4e38f;
        }
#pragma unroll 1
        for (int j = 0; j < NVP; j += 4) {
            float4 t0 = s_t[j], t1 = s_t[j+1], t2 = s_t[j+2], t3 = s_t[j+3];
#pragma unroll
            for (int k = 0; k < CPT; ++k) {
                float d0 = fmaf(nax[k], t0.x, fmaf(nay[k], t0.y, fmaf(naz[k], t0.z, t0.w)));
                float d1 = fmaf(nax[k], t1.x, fmaf(nay[k], t1.y, fmaf(naz[k], t1.z, t1.w)));
                float d2 = fmaf(nax[k], t2.x, fmaf(nay[k], t2.y, fmaf(naz[k], t2.z, t2.w)));
                float d3 = fmaf(nax[k], t3.x, fmaf(nay[k], t3.y, fmaf(naz[k], t3.z, t3.w)));
                m[k] = fminf(fminf(m[k], fminf(d0, d1)), fminf(d2, d3));
            }
        }
        float local = 0.0f;
#pragma unroll
        for (int k = 0; k < CPT; ++k)
            if (valid[k]) local += fmaxf(a2[k] + m[k] - BIAS, 0.0f);
        atomicAdd(&s_red[0], local);
        __syncthreads();
        if (tid < 4) part[(size_t)blk * 4 + tid] = (tid == 0) ? s_red[0] : 0.0f;
    }
}

// ---------------- Tail: part row-sum + popc(rc&gc) + param/KLD + loss ---------
__global__ __launch_bounds__(256) void k_tail(const float* __restrict__ part,
                                              const unsigned int* __restrict__ rcW,
                                              const unsigned int* __restrict__ gcW,
                                              const float* __restrict__ mean,
                                              const float* __restrict__ log_var,
                                              const float* __restrict__ rp,
                                              const float* __restrict__ xp,
                                              float* __restrict__ out) {
    int tid = threadIdx.x;
    __shared__ float red[8];
    // 0 S_cmap, 1 N_cmap, 2 S_pen, 3 N_gt, 4 S_cham, 5 N_cons, 6 param, 7 kld
    if (tid < 8) red[tid] = 0.0f;
    __syncthreads();
    float l0=0, l1=0, l2=0, l3=0, l4=0;
    for (int r = tid; r < NROLE; r += 256) {
        const float* row = part + (size_t)r * 4;
        if (r < REC_BLOCKS)                 { l0 += row[0]; l1 += row[1]; l2 += row[2]; }
        else if (r < REC_BLOCKS + GT_BLOCKS){ l3 += row[0]; }
        else                                { l4 += row[0]; }
    }
    float l5 = 0.0f;
    for (int i = tid; i < 16384; i += 256)
        l5 += (float)__popc(rcW[i] & gcW[i]);
    float s_param = 0.0f, s_kld = 0.0f;
    for (int i = tid; i < NB * NPAR; i += 256) {
        float d = rp[i] - xp[i];
        s_param += d * d;
    }
    for (int i = tid; i < NB * NZ; i += 256) {
        float m = mean[i], lv = log_var[i];
        s_kld += 1.0f + lv - m * m - expf(lv);
    }
    atomicAdd(&red[0], l0);
    atomicAdd(&red[1], l1);
    atomicAdd(&red[2], l2);
    atomicAdd(&red[3], l3);
    atomicAdd(&red[4], l4);
    atomicAdd(&red[5], l5);
    atomicAdd(&red[6], s_param);
    atomicAdd(&red[7], s_kld);
    __syncthreads();
    if (tid == 0) {
        const float fB = 64.0f;
        float param_loss  = red[6] / fB;
        float KLD         = -0.5f * red[7] / fB * 10.0f;
        float recon_loss  = red[4] / fB;
        float cmap_loss   = 3000.0f * red[0] / (fB * red[1]);
        float consistency = -5.0f * red[5] / (red[3] + 0.0001f);
        float penetr      = 100.0f * red[2] / fB;
        out[0] = (recon_loss + KLD) + 0.1f * param_loss + 1000.0f * cmap_loss
               + 10.0f * consistency + 10.0f * penetr;
    }
}

extern "C" void kernel_launch(void* const* d_in, const int* in_sizes, int n_in,
                              void* d_out, int out_size, void* d_ws, size_t ws_size,
                              hipStream_t stream) {
    (void)in_sizes; (void)n_in; (void)out_size; (void)ws_size;
    const float* obj     = (const float*)d_in[0];
    const float* recon   = (const float*)d_in[1];
    const float* gt      = (const float*)d_in[2];
    const float* mean    = (const float*)d_in[3];
    const float* log_var = (const float*)d_in[4];
    const float* rp      = (const float*)d_in[5];
    const float* xp      = (const float*)d_in[6];
    const int*   faces   = (const int*)d_in[7];
    float* part = (float*)d_ws + PART_OFF;
    unsigned char* rcA = (unsigned char*)((float*)d_ws + RC_OFF);
    unsigned char* gcA = (unsigned char*)((float*)d_ws + GC_OFF);
    float* out  = (float*)d_out;

    k_all <<<NROLE, 256, 0, stream>>>(obj, recon, gt, faces, part, rcA, gcA);
    k_tail<<<1,     256, 0, stream>>>(part, (const unsigned int*)rcA,
                                      (const unsigned int*)gcA,
                                      mean, log_var, rp, xp, out);
}

// Round 14
// 206.630 us; speedup vs baseline: 1.0064x; 1.0064x over previous
//
#include <hip/hip_runtime.h>
#include <math.h>

// Problem constants
#define NB     64
#define N1V    8192
#define NPTS   (NB * N1V)
#define NV     778
#define NVP    780
#define NFACE  1538
#define NZ     64
#define NPAR   61
#define NPRIOR 204
#define PPT    4        // points per thread (rec/gt roles)
#define GRES   8        // grid 8x8x8
#define GH     0.0125f  // cell size (domain [0,0.1])
#define GINV   80.0f
#define SLACK  1e-6f    // conservative fp slack on d^2 pruning
#define BIAS   0.0625f  // chamfer role only

// roles
#define REC_BLOCKS 512                 // (batch, chunk-of-1024)
#define GT_BLOCKS  512
#define CH_BLOCKS  128                 // (batch, dir)
#define NROLE (REC_BLOCKS + GT_BLOCKS + CH_BLOCKS)   // 1152
#define CMB_BLOCKS 64

// ws per-batch float4 layout (stride BATCH_F4):
//   [0,780)      recS  sorted-by-cell rec verts (x,y,z,|t|^2)
//   [780,1560)   nrmS  normals in same sorted order
//   [1560,2340)  gtS   sorted-by-cell gt verts
//   [2340,2544)  priS  prior verts (original order subset)
//   [2544,2674)  cell-start tables: rec_cs[513] u16, gt_cs at +520 u16
#define BATCH_F4 2688
#define ACC_OFF (NB * BATCH_F4 * 4)   // acc[16]: [2..7] sums, [15] ticket
#define RC_OFF  (ACC_OFF + 16)        // uchar[NPTS/4] rec-cmap nibbles
#define GC_OFF  (RC_OFF + 32768)      // uchar[NPTS/4] gt-cmap nibbles
// acc slots: 2 chamfer, 3 S_cmap, 4 N_cmap, 5 N_gt, 6 N_cons, 7 S_pen

__device__ __constant__ int c_prior[NPRIOR] = {
  697,698,699,700,712,713,714,715,737,738,739,740,741,743,744,745,746,748,749,750,
  753,754,755,756,757,758,759,760,761,762,763,764,765,766,767,768,
  46,47,48,49,164,165,166,167,194,195,223,237,238,280,281,298,301,317,320,323,
  324,325,326,327,328,329,330,331,332,333,340,341,342,343,344,345,346,347,348,349,
  350,351,352,353,354,355,
  356,357,358,359,375,376,386,387,396,397,402,403,413,429,433,434,435,436,437,438,
  439,440,441,442,443,444,452,453,454,455,456,459,460,461,462,463,464,465,466,467,
  468,469,470,471,484,485,486,496,497,506,507,513,514,524,545,546,547,548,549,550,
  551,552,553,555,563,564,565,566,567,570,572,573,574,575,576,577,578,
  580,581,582,583,600,601,602,614,615,624,625,630,631,641,663,664,665,666,667,668,
  670,672,680,681,682,683,684,686,687,688,689,690,691,692,693,694,695,
  73,96,98,99,772,774,775,777
};

__device__ __forceinline__ int cell_of(float x, float y, float z) {
    int cx = (int)(x * GINV); cx = min(GRES - 1, max(0, cx));
    int cy = (int)(y * GINV); cy = min(GRES - 1, max(0, cy));
    int cz = (int)(z * GINV); cz = min(GRES - 1, max(0, cz));
    return (cz * GRES + cy) * GRES + cx;
}

// exact grid NN: scan 3^3, prove with AABB bound (domain faces excluded),
// else 5^3, else full scan. Winner distance = identical fma chain -> exact.
template<bool WIDX>
__device__ __forceinline__ float grid_min(float px, float py, float pz,
                                          float nax, float nay, float naz, float a2,
                                          const float4* __restrict__ sp,
                                          const unsigned short* __restrict__ cs,
                                          int* bi_out) {
    int cx = (int)(px * GINV); cx = min(7, max(0, cx));
    int cy = (int)(py * GINV); cy = min(7, max(0, cy));
    int cz = (int)(pz * GINV); cz = min(7, max(0, cz));
    float best = 3.4e38f; int bi = 0;
#pragma unroll 1
    for (int r = 1; r <= 2; ++r) {
        int x0 = max(0, cx - r), x1 = min(7, cx + r);
        int y0 = max(0, cy - r), y1 = min(7, cy + r);
        int z0 = max(0, cz - r), z1 = min(7, cz + r);
#pragma unroll 1
        for (int z = z0; z <= z1; ++z)
#pragma unroll 1
        for (int y = y0; y <= y1; ++y) {
            int base = (z * 8 + y) * 8;
            int s = cs[base + x0], e = cs[base + x1 + 1];   // x-contiguous run
#pragma unroll 1
            for (int t = s; t < e; ++t) {
                float4 q = sp[t];
                float d = fmaf(nax, q.x, fmaf(nay, q.y, fmaf(naz, q.z, q.w)));
                if (WIDX) { if (d < best) { best = d; bi = t; } }
                else best = fminf(best, d);
            }
        }
        float b0 = (cx - r >= 0) ? (px - (float)(cx - r) * GH) : 1e30f;
        float b1 = (cx + r <= 7) ? ((float)(cx + r + 1) * GH - px) : 1e30f;
        float b2 = (cy - r >= 0) ? (py - (float)(cy - r) * GH) : 1e30f;
        float b3 = (cy + r <= 7) ? ((float)(cy + r + 1) * GH - py) : 1e30f;
        float b4 = (cz - r >= 0) ? (pz - (float)(cz - r) * GH) : 1e30f;
        float b5 = (cz + r <= 7) ? ((float)(cz + r + 1) * GH - pz) : 1e30f;
        float bm = fminf(fminf(fminf(b0, b1), fminf(b2, b3)), fminf(b4, b5));
        if (a2 + best + SLACK < bm * bm) { if (WIDX) *bi_out = bi; return best; }
    }
    // ultimate fallback: provably exact full scan
#pragma unroll 1
    for (int t = 0; t < NV; ++t) {
        float4 q = sp[t];
        float d = fmaf(nax, q.x, fmaf(nay, q.y, fmaf(naz, q.z, q.w)));
        if (WIDX) { if (d < best) { best = d; bi = t; } }
        else best = fminf(best, d);
    }
    if (WIDX) *bi_out = bi;
    return best;
}

// ---------------- Kernel 0: normals + two sorted grids + prior + acc init ----
__global__ __launch_bounds__(256) void k_prep(const float* __restrict__ recon,
                                              const float* __restrict__ gt,
                                              const int* __restrict__ faces,
                                              float4* __restrict__ ws4,
                                              float* __restrict__ acc) {
    int b = blockIdx.x, tid = threadIdx.x;
    if (b == 0 && tid < 16) acc[tid] = 0.0f;
    __shared__ float4 s_r[NV];
    __shared__ float s_vnx[NV], s_vny[NV], s_vnz[NV];
    __shared__ unsigned int s_cnt[512];
    __shared__ unsigned short s_start[513];

    float4* base4 = ws4 + (size_t)b * BATCH_F4;
    float4* recS = base4;
    float4* nrmS = base4 + NVP;
    float4* gtS  = base4 + 2 * NVP;
    float4* priS = base4 + 3 * NVP;
    unsigned short* rcs = (unsigned short*)(base4 + 2544 / 4 * 4 + 0);  // = base4+2544? keep simple:
    rcs = (unsigned short*)(ws4 + (size_t)b * BATCH_F4 + 2544);
    unsigned short* gcs = rcs + 520;

    const float* rb = recon + (size_t)b * NV * 3;
    const float* gb = gt    + (size_t)b * NV * 3;

    // ---------- phase A: rec ----------
    for (int j = tid; j < NV; j += 256) {
        float x = rb[3*j], y = rb[3*j+1], z = rb[3*j+2];
        s_r[j] = make_float4(x, y, z, x*x + y*y + z*z);
        s_vnx[j] = 0.0f; s_vny[j] = 0.0f; s_vnz[j] = 0.0f;
    }
    s_cnt[tid] = 0u; s_cnt[tid + 256] = 0u;
    __syncthreads();
    for (int f = tid; f < NFACE; f += 256) {
        int i0 = faces[3*f], i1 = faces[3*f+1], i2 = faces[3*f+2];
        float4 p0 = s_r[i0], p1 = s_r[i1], p2 = s_r[i2];
        float e1x = p1.x - p0.x, e1y = p1.y - p0.y, e1z = p1.z - p0.z;
        float e2x = p2.x - p0.x, e2y = p2.y - p0.y, e2z = p2.z - p0.z;
        float fx = e1y * e2z - e1z * e2y;
        float fy = e1z * e2x - e1x * e2z;
        float fz = e1x * e2y - e1y * e2x;
        atomicAdd(&s_vnx[i0], fx); atomicAdd(&s_vny[i0], fy); atomicAdd(&s_vnz[i0], fz);
        atomicAdd(&s_vnx[i1], fx); atomicAdd(&s_vny[i1], fy); atomicAdd(&s_vnz[i1], fz);
        atomicAdd(&s_vnx[i2], fx); atomicAdd(&s_vny[i2], fy); atomicAdd(&s_vnz[i2], fz);
    }
    __syncthreads();
    for (int j = tid; j < NV; j += 256) {
        float x = s_vnx[j], y = s_vny[j], z = s_vnz[j];
        float inv = 1.0f / (sqrtf(x*x + y*y + z*z) + 1e-12f);
        s_vnx[j] = x * inv; s_vny[j] = y * inv; s_vnz[j] = z * inv;
    }
    for (int j = tid; j < NV; j += 256) {
        float4 v = s_r[j];
        atomicAdd(&s_cnt[cell_of(v.x, v.y, v.z)], 1u);
    }
    __syncthreads();
    // inclusive scan over 512 (Hillis-Steele, 2 idx/thread)
    for (int off = 1; off < 512; off <<= 1) {
        unsigned int a0 = (tid >= off) ? s_cnt[tid - off] : 0u;
        int i2 = tid + 256;
        unsigned int a1 = (i2 >= off) ? s_cnt[i2 - off] : 0u;
        __syncthreads();
        s_cnt[tid] += a0; s_cnt[i2] += a1;
        __syncthreads();
    }
    if (tid == 0) s_start[0] = 0;
    s_start[tid + 1]   = (unsigned short)s_cnt[tid];
    s_start[tid + 257] = (unsigned short)s_cnt[tid + 256];
    __syncthreads();
    rcs[tid] = s_start[tid]; rcs[tid + 256] = s_start[tid + 256];
    if (tid == 0) rcs[512] = s_start[512];
    s_cnt[tid] = 0u; s_cnt[tid + 256] = 0u;
    __syncthreads();
    for (int j = tid; j < NV; j += 256) {
        float4 v = s_r[j];
        int c = cell_of(v.x, v.y, v.z);
        int pos = (int)s_start[c] + (int)atomicAdd(&s_cnt[c], 1u);
        recS[pos] = v;
        nrmS[pos] = make_float4(s_vnx[j], s_vny[j], s_vnz[j], 0.0f);
    }
    for (int k = tid; k < NPRIOR; k += 256) priS[k] = s_r[c_prior[k]];
    __syncthreads();

    // ---------- phase B: gt ----------
    for (int j = tid; j < NV; j += 256) {
        float x = gb[3*j], y = gb[3*j+1], z = gb[3*j+2];
        s_r[j] = make_float4(x, y, z, x*x + y*y + z*z);
    }
    s_cnt[tid] = 0u; s_cnt[tid + 256] = 0u;
    __syncthreads();
    for (int j = tid; j < NV; j += 256) {
        float4 v = s_r[j];
        atomicAdd(&s_cnt[cell_of(v.x, v.y, v.z)], 1u);
    }
    __syncthreads();
    for (int off = 1; off < 512; off <<= 1) {
        unsigned int a0 = (tid >= off) ? s_cnt[tid - off] : 0u;
        int i2 = tid + 256;
        unsigned int a1 = (i2 >= off) ? s_cnt[i2 - off] : 0u;
        __syncthreads();
        s_cnt[tid] += a0; s_cnt[i2] += a1;
        __syncthreads();
    }
    if (tid == 0) s_start[0] = 0;
    s_start[tid + 1]   = (unsigned short)s_cnt[tid];
    s_start[tid + 257] = (unsigned short)s_cnt[tid + 256];
    __syncthreads();
    gcs[tid] = s_start[tid]; gcs[tid + 256] = s_start[tid + 256];
    if (tid == 0) gcs[512] = s_start[512];
    s_cnt[tid] = 0u; s_cnt[tid + 256] = 0u;
    __syncthreads();
    for (int j = tid; j < NV; j += 256) {
        float4 v = s_r[j];
        int c = cell_of(v.x, v.y, v.z);
        int pos = (int)s_start[c] + (int)atomicAdd(&s_cnt[c], 1u);
        gtS[pos] = v;
    }
}

#define LOAD_PTS4(ob)                                                         \
    const float4* ob4 = (const float4*)((ob) + (size_t)tid * 12);             \
    float4 q0 = ob4[0], q1 = ob4[1], q2 = ob4[2];                             \
    float px[PPT], py[PPT], pz[PPT];                                          \
    px[0]=q0.x; py[0]=q0.y; pz[0]=q0.z;  px[1]=q0.w; py[1]=q1.x; pz[1]=q1.y;  \
    px[2]=q1.z; py[2]=q1.w; pz[2]=q2.x;  px[3]=q2.y; py[3]=q2.z; pz[3]=q2.w;

// ---------------- Fused role kernel ----------------
__global__ __launch_bounds__(256) void k_fused(const float* __restrict__ obj,
                                               const float4* __restrict__ ws4,
                                               float* __restrict__ acc,
                                               unsigned char* __restrict__ rcA,
                                               unsigned char* __restrict__ gcA) {
    __shared__ float4 s_pts[NVP];
    __shared__ float4 s_pri[NPRIOR];
    __shared__ unsigned short s_cs[514];
    __shared__ float s_red[3];
    int tid = threadIdx.x;
    int blk = blockIdx.x;

    if (blk < REC_BLOCKS) {
        // ============ REC ROLE: grid argmin + brute prior + epilogue ========
        int b = blk >> 3, chunk = blk & 7;
        const float4* base4 = ws4 + (size_t)b * BATCH_F4;
        const unsigned short* rcs = (const unsigned short*)(ws4 + (size_t)b * BATCH_F4 + 2544);
        for (int j = tid; j < NV; j += 256) s_pts[j] = base4[j];
        for (int k = tid; k < NPRIOR; k += 256) s_pri[k] = base4[3 * NVP + k];
        if (tid < 3) s_red[tid] = 0.0f;
        for (int t = tid; t < 513; t += 256) s_cs[t] = rcs[t];
        __syncthreads();

        const float* ob = obj + ((size_t)b * N1V + (size_t)chunk * 1024) * 3;
        LOAD_PTS4(ob)
        float nax[PPT], nay[PPT], naz[PPT], a2[PPT], mpri[PPT];
#pragma unroll
        for (int i = 0; i < PPT; ++i) {
            nax[i] = -2.0f * px[i]; nay[i] = -2.0f * py[i]; naz[i] = -2.0f * pz[i];
            a2[i] = px[i]*px[i] + py[i]*py[i] + pz[i]*pz[i];
            mpri[i] = 3.4e38f;
        }
        // prior: brute broadcast scan (204 = 51 quads)
#pragma unroll 1
        for (int jq = 0; jq < NPRIOR / 4; ++jq) {
            int j = 4 * jq;
            float4 t0 = s_pri[j], t1 = s_pri[j+1], t2 = s_pri[j+2], t3 = s_pri[j+3];
#pragma unroll
            for (int i = 0; i < PPT; ++i) {
                float d0 = fmaf(nax[i], t0.x, fmaf(nay[i], t0.y, fmaf(naz[i], t0.z, t0.w)));
                float d1 = fmaf(nax[i], t1.x, fmaf(nay[i], t1.y, fmaf(naz[i], t1.z, t1.w)));
                float d2 = fmaf(nax[i], t2.x, fmaf(nay[i], t2.y, fmaf(naz[i], t2.z, t2.w)));
                float d3 = fmaf(nax[i], t3.x, fmaf(nay[i], t3.y, fmaf(naz[i], t3.z, t3.w)));
                mpri[i] = fminf(fminf(mpri[i], fminf(d0, d1)), fminf(d2, d3));
            }
        }
        float lS_cmap = 0.0f, lN_cmap = 0.0f, lS_pen = 0.0f;
        unsigned int rcbits = 0;
        const float4* nrmG = base4 + NVP;
#pragma unroll 1
        for (int i = 0; i < PPT; ++i) {
            int bi;
            float bp = grid_min<true>(px[i], py[i], pz[i], nax[i], nay[i], naz[i],
                                      a2[i], s_pts, s_cs, &bi);
            float drec = fmaxf(a2[i] + bp, 0.0f);
            float dpri = fmaxf(a2[i] + mpri[i], 0.0f);
            if (drec < 1e-4f) { lS_cmap += dpri; lN_cmap += 1.0f; }
            if (sqrtf(drec) < 0.005f) rcbits |= (1u << i);
            float4 tS = s_pts[bi];
            float4 nr = nrmG[bi];
            float ddot = (tS.x - px[i]) * nr.x + (tS.y - py[i]) * nr.y
                       + (tS.z - pz[i]) * nr.z;
            if (ddot > 0.0f) lS_pen += drec;
        }
        rcA[(size_t)blk * 256 + tid] = (unsigned char)rcbits;
        atomicAdd(&s_red[0], lS_cmap);
        atomicAdd(&s_red[1], lN_cmap);
        atomicAdd(&s_red[2], lS_pen);
        __syncthreads();
        if (tid == 0) atomicAdd(&acc[3], s_red[0]);
        if (tid == 1) atomicAdd(&acc[4], s_red[1]);
        if (tid == 2) atomicAdd(&acc[7], s_red[2]);
        return;
    }

    if (blk < REC_BLOCKS + GT_BLOCKS) {
        // ============ GT ROLE: grid min + gc bits ============
        int r = blk - REC_BLOCKS;
        int b = r >> 3, chunk = r & 7;
        const float4* base4 = ws4 + (size_t)b * BATCH_F4;
        const unsigned short* gcs = (const unsigned short*)(ws4 + (size_t)b * BATCH_F4 + 2544) + 520;
        for (int j = tid; j < NV; j += 256) s_pts[j] = base4[2 * NVP + j];
        for (int t = tid; t < 513; t += 256) s_cs[t] = gcs[t];
        if (tid == 0) s_red[0] = 0.0f;
        __syncthreads();

        const float* ob = obj + ((size_t)b * N1V + (size_t)chunk * 1024) * 3;
        LOAD_PTS4(ob)
        float lN_gt = 0.0f;
        unsigned int gcbits = 0;
#pragma unroll 1
        for (int i = 0; i < PPT; ++i) {
            float nax = -2.0f * px[i], nay = -2.0f * py[i], naz = -2.0f * pz[i];
            float a2 = px[i]*px[i] + py[i]*py[i] + pz[i]*pz[i];
            float bp = grid_min<false>(px[i], py[i], pz[i], nax, nay, naz,
                                       a2, s_pts, s_cs, (int*)0);
            float dgt = fmaxf(a2 + bp, 0.0f);
            if (sqrtf(dgt) < 0.005f) { lN_gt += 1.0f; gcbits |= (1u << i); }
        }
        gcA[(size_t)r * 256 + tid] = (unsigned char)gcbits;
        atomicAdd(&s_red[0], lN_gt);
        __syncthreads();
        if (tid == 0) atomicAdd(&acc[5], s_red[0]);
        return;
    }

    // ============ CHAMFER ROLE (brute, direct stage, 4 src/thread) ============
    {
        int c   = blk - (REC_BLOCKS + GT_BLOCKS);
        int b   = c >> 1;
        int dir = c & 1;           // 0: rec->gt, 1: gt->rec
        // stage targets from raw inputs
        extern const float* __unused_dummy;
        // note: recon/gt pointers passed via acc? no — use ws-free direct approach:
        // chamfer reads sorted arrays (any order works for min): rec = base4[0..],
        // gt = base4[2*NVP..] — already staged in ws with w=|t|^2.
        const float4* base4 = ws4 + (size_t)b * BATCH_F4;
        const float4* srcv = dir ? (base4 + 2 * NVP) : base4;   // gtS : recS
        const float4* tgtv = dir ? base4 : (base4 + 2 * NVP);   // recS : gtS
        for (int j = tid; j < NV; j += 256) s_pts[j] = tgtv[j];
        if (tid < 2) s_pts[NV + tid] = make_float4(0.f, 0.f, 0.f, 1e30f);
        if (tid == 0) s_red[0] = 0.0f;
        __syncthreads();

        const int CPT = 4;
        float nax[CPT], nay[CPT], naz[CPT], a2s[CPT], m[CPT];
        bool valid[CPT];
#pragma unroll
        for (int k = 0; k < CPT; ++k) {
            int p = tid + 256 * k;
            valid[k] = (p < NV);
            float4 s = srcv[valid[k] ? p : 0];
            nax[k] = -2.0f * s.x; nay[k] = -2.0f * s.y; naz[k] = -2.0f * s.z;
            a2s[k] = s.x*s.x + s.y*s.y + s.z*s.z;
            m[k] = 3.4e38f;
        }
#pragma unroll 1
        for (int j = 0; j < NVP; j += 4) {
            float4 t0 = s_pts[j], t1 = s_pts[j+1], t2 = s_pts[j+2], t3 = s_pts[j+3];
#pragma unroll
            for (int k = 0; k < CPT; ++k) {
                float d0 = fmaf(nax[k], t0.x, fmaf(nay[k], t0.y, fmaf(naz[k], t0.z, t0.w)));
                float d1 = fmaf(nax[k], t1.x, fmaf(nay[k], t1.y, fmaf(naz[k], t1.z, t1.w)));
                float d2 = fmaf(nax[k], t2.x, fmaf(nay[k], t2.y, fmaf(naz[k], t2.z, t2.w)));
                float d3 = fmaf(nax[k], t3.x, fmaf(nay[k], t3.y, fmaf(naz[k], t3.z, t3.w)));
                m[k] = fminf(fminf(m[k], fminf(d0, d1)), fminf(d2, d3));
            }
        }
        float local = 0.0f;
#pragma unroll
        for (int k = 0; k < CPT; ++k)
            if (valid[k]) local += fmaxf(a2s[k] + m[k], 0.0f);
        atomicAdd(&s_red[0], local);
        __syncthreads();
        if (tid == 0) atomicAdd(&acc[2], s_red[0]);
    }
}

// ---------------- Combine (popc rc&gc) + finalize (ticket) ----------------
__global__ __launch_bounds__(256) void k_combine(float* __restrict__ acc,
                                                 const unsigned int* __restrict__ rcW,
                                                 const unsigned int* __restrict__ gcW,
                                                 const float* __restrict__ mean,
                                                 const float* __restrict__ log_var,
                                                 const float* __restrict__ rp,
                                                 const float* __restrict__ xp,
                                                 float* __restrict__ out) {
    int blk = blockIdx.x, tid = threadIdx.x;
    __shared__ float s_red[2];
    __shared__ unsigned int s_ticket;
    if (tid < 2) s_red[tid] = 0.0f;
    __syncthreads();
    float cnt = 0.0f;
    for (int i = blk * 256 + tid; i < 32768; i += CMB_BLOCKS * 256)
        cnt += (float)__popc(rcW[i] & gcW[i]);
    atomicAdd(&s_red[0], cnt);
    __syncthreads();
    if (tid == 0) atomicAdd(&acc[6], s_red[0]);
    __threadfence();
    if (tid == 0) s_ticket = atomicAdd((unsigned int*)&acc[15], 1u);
    __syncthreads();

    if (s_ticket == CMB_BLOCKS - 1) {
        if (tid < 2) s_red[tid] = 0.0f;
        __syncthreads();
        float s_param = 0.0f, s_kld = 0.0f;
        for (int i = tid; i < NB * NPAR; i += 256) {
            float d = rp[i] - xp[i];
            s_param += d * d;
        }
        for (int i = tid; i < NB * NZ; i += 256) {
            float m = mean[i], lv = log_var[i];
            s_kld += 1.0f + lv - m * m - expf(lv);
        }
        atomicAdd(&s_red[0], s_param);
        atomicAdd(&s_red[1], s_kld);
        __syncthreads();
        if (tid == 0) {
            const float fB = 64.0f;
            float a2v = atomicAdd(&acc[2], 0.0f);
            float a3  = atomicAdd(&acc[3], 0.0f);
            float a4  = atomicAdd(&acc[4], 0.0f);
            float a5  = atomicAdd(&acc[5], 0.0f);
            float a6  = atomicAdd(&acc[6], 0.0f);
            float a7  = atomicAdd(&acc[7], 0.0f);
            float param_loss  = s_red[0] / fB;
            float KLD         = -0.5f * s_red[1] / fB * 10.0f;
            float recon_loss  = a2v / fB;
            float cmap_loss   = 3000.0f * a3 / (fB * a4);
            float consistency = -5.0f * a6 / (a5 + 0.0001f);
            float penetr      = 100.0f * a7 / fB;
            out[0] = (recon_loss + KLD) + 0.1f * param_loss + 1000.0f * cmap_loss
                   + 10.0f * consistency + 10.0f * penetr;
        }
    }
}

extern "C" void kernel_launch(void* const* d_in, const int* in_sizes, int n_in,
                              void* d_out, int out_size, void* d_ws, size_t ws_size,
                              hipStream_t stream) {
    (void)in_sizes; (void)n_in; (void)out_size; (void)ws_size;
    const float* obj     = (const float*)d_in[0];
    const float* recon   = (const float*)d_in[1];
    const float* gt      = (const float*)d_in[2];
    const float* mean    = (const float*)d_in[3];
    const float* log_var = (const float*)d_in[4];
    const float* rp      = (const float*)d_in[5];
    const float* xp      = (const float*)d_in[6];
    const int*   faces   = (const int*)d_in[7];
    float4* ws4 = (float4*)d_ws;
    float* acc  = (float*)d_ws + ACC_OFF;
    unsigned char* rcA = (unsigned char*)((float*)d_ws + RC_OFF);
    unsigned char* gcA = (unsigned char*)((float*)d_ws + GC_OFF);
    float* out  = (float*)d_out;

    k_prep   <<<NB,         256, 0, stream>>>(recon, gt, faces, ws4, acc);
    k_fused  <<<NROLE,      256, 0, stream>>>(obj, ws4, acc, rcA, gcA);
    k_combine<<<CMB_BLOCKS, 256, 0, stream>>>(acc, (const unsigned int*)rcA,
                                              (const unsigned int*)gcA,
                                              mean, log_var, rp, xp, out);
}